// Round 1
// baseline (58.149 us; speedup 1.0000x reference)
//
#include <hip/hip_runtime.h>

#define NTOT 8192
#define TI 256   // i-rows per block (= block threads)
#define TJ 512   // j-columns per block chunk (staged in LDS)

// Each block: 256 consecutive i values x 512 consecutive j values.
// valid pair: j > i && group[j] == group[i]; loss = softplus(s_j - s_i).
__global__ __launch_bounds__(TI) void rankloss_pairs(
    const float* __restrict__ score, const int* __restrict__ gid,
    float* __restrict__ acc)  // acc[0]=loss sum, acc[1]=pair count
{
  const int ibase = blockIdx.x * TI;
  const int j0    = blockIdx.y * TJ;
  // If the largest j in this chunk is <= the smallest i in this tile,
  // no pair has j > i: skip the whole block.
  if (j0 + TJ - 1 <= ibase) return;

  __shared__ float s_s[TJ];
  __shared__ int   s_g[TJ];
  for (int t = threadIdx.x; t < TJ; t += TI) {
    s_s[t] = score[j0 + t];
    s_g[t] = gid[j0 + t];
  }
  __syncthreads();

  const int   i  = ibase + threadIdx.x;
  const float si = score[i];
  const int   gi = gid[i];

  float sum = 0.f;
  float cnt = 0.f;
  #pragma unroll 4
  for (int t = 0; t < TJ; ++t) {
    const int   j = j0 + t;
    const float x = s_s[t] - si;                 // s_j - s_i
    // stable softplus(x) = max(x,0) + log(1 + exp(-|x|))
    const float sp = fmaxf(x, 0.f) + __logf(1.f + __expf(-fabsf(x)));
    const bool valid = (j > i) & (s_g[t] == gi);
    sum += valid ? sp : 0.f;
    cnt += valid ? 1.f : 0.f;
  }

  // wave(64) shuffle reduction, then cross-wave via LDS
  for (int off = 32; off > 0; off >>= 1) {
    sum += __shfl_down(sum, off, 64);
    cnt += __shfl_down(cnt, off, 64);
  }
  __shared__ float red[(TI / 64) * 2];
  const int wid  = threadIdx.x >> 6;
  const int lane = threadIdx.x & 63;
  if (lane == 0) { red[wid * 2] = sum; red[wid * 2 + 1] = cnt; }
  __syncthreads();
  if (threadIdx.x == 0) {
    float ts = 0.f, tc = 0.f;
    #pragma unroll
    for (int w = 0; w < TI / 64; ++w) { ts += red[w * 2]; tc += red[w * 2 + 1]; }
    atomicAdd(&acc[0], ts);
    atomicAdd(&acc[1], tc);
  }
}

__global__ void rankloss_final(const float* __restrict__ acc, float* __restrict__ out) {
  out[0] = acc[0] / acc[1];
}

extern "C" void kernel_launch(void* const* d_in, const int* in_sizes, int n_in,
                              void* d_out, int out_size, void* d_ws, size_t ws_size,
                              hipStream_t stream) {
  const float* score = (const float*)d_in[0];
  const int*   gid   = (const int*)d_in[1];
  float* acc = (float*)d_ws;

  hipMemsetAsync(acc, 0, 2 * sizeof(float), stream);

  dim3 grid(NTOT / TI, NTOT / TJ);
  rankloss_pairs<<<grid, dim3(TI), 0, stream>>>(score, gid, acc);
  rankloss_final<<<1, 1, 0, stream>>>(acc, (float*)d_out);
}

// Round 2
// 21.462 us; speedup vs baseline: 2.7094x; 2.7094x over previous
//
#include <hip/hip_runtime.h>

#define NTOT 8192
#define NG   64
#define MAXM 512   // per-group capacity; actual m ~ Binomial(8192,1/64) ≈ 128 ± 11
#define BT   256   // threads per block (4 waves)

// One block per group g:
//  Phase A: each wave ballot-compacts its quarter of the array (stable order)
//           into LDS -> s_s[0..m) holds group-g scores in original index order.
//  Phase B: all threads compute sum over a<b of softplus(s_s[b]-s_s[a]).
//  Writes partial[2g]=loss_sum, partial[2g+1]=pair count. No atomics.
__global__ __launch_bounds__(BT) void rankloss_grouped(
    const float* __restrict__ score, const int* __restrict__ gid,
    float* __restrict__ partial)
{
  const int g    = blockIdx.x;
  const int tid  = threadIdx.x;
  const int wid  = tid >> 6;
  const int lane = tid & 63;

  __shared__ float s_s[MAXM];
  __shared__ int   s_wcnt[4];
  __shared__ float s_red[4];

  const int qbase = wid * (NTOT / 4);

  // ---- Phase A, pass 1: count matches in this wave's quarter ----
  int cnt = 0;
  #pragma unroll 4
  for (int c = 0; c < (NTOT / 4); c += 64) {
    const int gv = gid[qbase + c + lane];
    cnt += __popcll(__ballot(gv == g));
  }
  if (lane == 0) s_wcnt[wid] = cnt;
  __syncthreads();

  int base = 0;
  for (int w = 0; w < wid; ++w) base += s_wcnt[w];
  const int m = s_wcnt[0] + s_wcnt[1] + s_wcnt[2] + s_wcnt[3];

  // ---- Phase A, pass 2: stable compaction into LDS (L1-warm reload) ----
  const unsigned long long below = (1ull << lane) - 1ull;
  int wbase = base;
  #pragma unroll 4
  for (int c = 0; c < (NTOT / 4); c += 64) {
    const int   idx = qbase + c + lane;
    const int   gv  = gid[idx];
    const float sv  = score[idx];
    const unsigned long long mask = __ballot(gv == g);
    if (gv == g) {
      const int pos = wbase + __popcll(mask & below);
      if (pos < MAXM) s_s[pos] = sv;
    }
    wbase += __popcll(mask);
  }
  __syncthreads();

  // ---- Phase B: pairwise softplus over LDS ----
  // thread t handles rows a = (t>>2) + 64k, columns b = a+1+(t&3) step 4
  float sum = 0.f;
  const int rcol = tid & 3;
  for (int a = (tid >> 2); a < m; a += 64) {
    const float sa = s_s[a];
    for (int b = a + 1 + rcol; b < m; b += 4) {
      const float x = s_s[b] - sa;           // s_j - s_i, j>i
      sum += fmaxf(x, 0.f) + __logf(1.f + __expf(-fabsf(x)));
    }
  }

  // ---- Phase C: block reduction ----
  for (int off = 32; off > 0; off >>= 1) sum += __shfl_down(sum, off, 64);
  if (lane == 0) s_red[wid] = sum;
  __syncthreads();
  if (tid == 0) {
    const float ts = s_red[0] + s_red[1] + s_red[2] + s_red[3];
    partial[2 * g]     = ts;
    partial[2 * g + 1] = 0.5f * (float)m * (float)(m - 1);
  }
}

// 64 partials -> scalar mean; exactly one wave.
__global__ void rankloss_final(const float* __restrict__ partial, float* __restrict__ out) {
  const int lane = threadIdx.x;
  float s = partial[2 * lane];
  float c = partial[2 * lane + 1];
  for (int off = 32; off > 0; off >>= 1) {
    s += __shfl_down(s, off, 64);
    c += __shfl_down(c, off, 64);
  }
  if (lane == 0) out[0] = s / c;
}

extern "C" void kernel_launch(void* const* d_in, const int* in_sizes, int n_in,
                              void* d_out, int out_size, void* d_ws, size_t ws_size,
                              hipStream_t stream) {
  const float* score = (const float*)d_in[0];
  const int*   gid   = (const int*)d_in[1];
  float* partial = (float*)d_ws;   // 128 floats, fully overwritten each call

  rankloss_grouped<<<NG, BT, 0, stream>>>(score, gid, partial);
  rankloss_final<<<1, 64, 0, stream>>>(partial, (float*)d_out);
}